// Round 3
// baseline (498.258 us; speedup 1.0000x reference)
//
#include <hip/hip_runtime.h>
#include <cstdint>
#include <cstddef>

#define NB 4
#define NQ 8192
#define ND 256
#define NH 8
#define NL 4
#define NP 4
#define QBLK 16
// HD = 32

// ---------------- transpose (B, D, HW) -> (B, HW, D) ----------------
__global__ __launch_bounds__(256) void transpose_k(
    const float* __restrict__ in, float* __restrict__ out, int HW) {
  __shared__ float tile[32][33];
  int yx0 = blockIdx.x << 5;
  int d0  = blockIdx.y << 5;
  int b   = blockIdx.z;
  const float* inb = in + (size_t)b * ND * HW;
  float* outb = out + (size_t)b * HW * ND;
  int col = threadIdx.x & 31;
  int row = threadIdx.x >> 5;  // 0..7
#pragma unroll
  for (int r = 0; r < 4; ++r) {
    int d = row + (r << 3);
    tile[d][col] = inb[(size_t)(d0 + d) * HW + (yx0 + col)];
  }
  __syncthreads();
#pragma unroll
  for (int r = 0; r < 4; ++r) {
    int y = row + (r << 3);
    outb[(size_t)(yx0 + y) * ND + (d0 + col)] = tile[col][y];
  }
}

// ---------------- proj: offsets(tanh)+ref -> pos, logits -> softmax attn ----
// block = 192 threads, handles QBLK=16 queries.
// threads 0..127 : offset GEMM, slot=(t&63) -> 4 cols, qgroup=(t>>6) -> 8 queries
// threads 128..191: attn GEMM, slot=(u&31) -> 4 cols, qgroup=(u>>5) -> 8 queries
__global__ __launch_bounds__(192) void proj_k(
    const float* __restrict__ query, const float* __restrict__ refp,
    const float* __restrict__ W_off, const float* __restrict__ b_off,
    const float* __restrict__ W_attn, const float* __restrict__ b_attn,
    float* __restrict__ pos, float* __restrict__ attn_out) {
  int q0 = blockIdx.x * QBLK;
  __shared__ float qs[QBLK][ND];
  __shared__ float lg[QBLK][128];
  int t = threadIdx.x;
  {
    const float4* qsrc = (const float4*)(query + (size_t)q0 * ND);
    float4* qdst = (float4*)&qs[0][0];
#pragma unroll
    for (int i = 0; i < 6; ++i) {
      int idx = t + 192 * i;
      if (idx < QBLK * ND / 4) qdst[idx] = qsrc[idx];
    }
  }
  __syncthreads();
  if (t < 128) {
    int slot = t & 63, qg = t >> 6;
    int j0 = slot << 2;
    float4 bb = *(const float4*)(b_off + j0);
    float4 acc[8];
#pragma unroll
    for (int qq = 0; qq < 8; ++qq) acc[qq] = bb;
    const float* qbase = &qs[qg * 8][0];
#pragma unroll 4
    for (int k = 0; k < ND; ++k) {
      float4 w = *(const float4*)(W_off + (size_t)k * 256 + j0);
#pragma unroll
      for (int qq = 0; qq < 8; ++qq) {
        float qk = qbase[qq * ND + k];
        acc[qq].x = fmaf(qk, w.x, acc[qq].x);
        acc[qq].y = fmaf(qk, w.y, acc[qq].y);
        acc[qq].z = fmaf(qk, w.z, acc[qq].z);
        acc[qq].w = fmaf(qk, w.w, acc[qq].w);
      }
    }
#pragma unroll
    for (int qq = 0; qq < 8; ++qq) {
      int bq = q0 + qg * 8 + qq;
      float rx = refp[bq * 2 + 0] * 2.f - 1.f;
      float ry = refp[bq * 2 + 1] * 2.f - 1.f;
      float4 r;
      r.x = rx + tanhf(acc[qq].x);
      r.y = ry + tanhf(acc[qq].y);
      r.z = rx + tanhf(acc[qq].z);
      r.w = ry + tanhf(acc[qq].w);
      *(float4*)(pos + (size_t)bq * 256 + j0) = r;
    }
  } else {
    int u = t - 128;
    int slot = u & 31, qg = u >> 5;
    int j0 = slot << 2;
    float4 bb = *(const float4*)(b_attn + j0);
    float4 acc[8];
#pragma unroll
    for (int qq = 0; qq < 8; ++qq) acc[qq] = bb;
    const float* qbase = &qs[qg * 8][0];
#pragma unroll 4
    for (int k = 0; k < ND; ++k) {
      float4 w = *(const float4*)(W_attn + (size_t)k * 128 + j0);
#pragma unroll
      for (int qq = 0; qq < 8; ++qq) {
        float qk = qbase[qq * ND + k];
        acc[qq].x = fmaf(qk, w.x, acc[qq].x);
        acc[qq].y = fmaf(qk, w.y, acc[qq].y);
        acc[qq].z = fmaf(qk, w.z, acc[qq].z);
        acc[qq].w = fmaf(qk, w.w, acc[qq].w);
      }
    }
#pragma unroll
    for (int qq = 0; qq < 8; ++qq) {
      int qi = qg * 8 + qq;
      lg[qi][j0 + 0] = acc[qq].x;
      lg[qi][j0 + 1] = acc[qq].y;
      lg[qi][j0 + 2] = acc[qq].z;
      lg[qi][j0 + 3] = acc[qq].w;
    }
  }
  __syncthreads();
  if (t < 128) {
    int qi = t >> 3;
    int h = t & 7;
    float* l = &lg[qi][h * 16];
    float m = -1e30f;
#pragma unroll
    for (int i = 0; i < 16; ++i) m = fmaxf(m, l[i]);
    float e[16], s = 0.f;
#pragma unroll
    for (int i = 0; i < 16; ++i) { e[i] = __expf(l[i] - m); s += e[i]; }
    float inv = 1.f / s;
#pragma unroll
    for (int i = 0; i < 16; ++i) l[i] = e[i] * inv;
  }
  __syncthreads();
  {
    // coalesced copy-out of attention weights: QBLK*128 floats = 512 float4
    const float4* src = (const float4*)&lg[0][0];
    float4* dst = (float4*)(attn_out + (size_t)q0 * 128);
#pragma unroll
    for (int i = 0; i < 3; ++i) {
      int idx = t + 192 * i;
      if (idx < QBLK * 128 / 4) dst[idx] = src[idx];
    }
  }
}

// ---------------- sampling: per (b,q), thread = (head, channel) -----------
__global__ __launch_bounds__(256) void sample_k(
    const float* __restrict__ fT0, const float* __restrict__ fT1,
    const float* __restrict__ fT2, const float* __restrict__ fT3,
    const float* __restrict__ pos, const float* __restrict__ attnw,
    float* __restrict__ agg) {
  int bq = blockIdx.x;
  int b = bq >> 13;  // Q = 8192
  __shared__ float ps[256];
  __shared__ float as[128];
  int t = threadIdx.x;
  ps[t] = pos[(size_t)bq * 256 + t];
  if (t < 128) as[t] = attnw[(size_t)bq * 128 + t];
  __syncthreads();
  int h = t >> 5;
  int c = t & 31;
  int d = (h << 5) + c;
  const float* fts[4] = {
      fT0 + (size_t)b * 16384 * ND, fT1 + (size_t)b * 4096 * ND,
      fT2 + (size_t)b * 1024 * ND, fT3 + (size_t)b * 256 * ND};
  const int HFs[4] = {128, 64, 32, 16};
  const int WFs[4] = {128, 64, 32, 16};
  float acc = 0.f;
#pragma unroll
  for (int l = 0; l < 4; ++l) {
    const float* ft = fts[l];
    const int Hf = HFs[l], Wf = WFs[l];
#pragma unroll
    for (int p = 0; p < 4; ++p) {
      int idx = ((h * 4 + l) * 4 + p);
      float gx = ps[idx * 2 + 0];
      float gy = ps[idx * 2 + 1];
      float a = as[idx];
      float x = (gx + 1.f) * 0.5f * (float)(Wf - 1);
      float y = (gy + 1.f) * 0.5f * (float)(Hf - 1);
      float x0f = floorf(x), y0f = floorf(y);
      float wx1 = x - x0f, wx0 = 1.f - wx1;
      float wy1 = y - y0f, wy0 = 1.f - wy1;
      int x0 = (int)x0f, y0 = (int)y0f;
      int x1 = x0 + 1, y1 = y0 + 1;
      bool vx0 = (x0 >= 0) && (x0 <= Wf - 1);
      bool vx1 = (x1 >= 0) && (x1 <= Wf - 1);
      bool vy0 = (y0 >= 0) && (y0 <= Hf - 1);
      bool vy1 = (y1 >= 0) && (y1 <= Hf - 1);
      int xc0 = min(max(x0, 0), Wf - 1), xc1 = min(max(x1, 0), Wf - 1);
      int yc0 = min(max(y0, 0), Hf - 1), yc1 = min(max(y1, 0), Hf - 1);
      float v00 = ft[((size_t)(yc0 * Wf + xc0)) * ND + d];
      float v10 = ft[((size_t)(yc0 * Wf + xc1)) * ND + d];
      float v01 = ft[((size_t)(yc1 * Wf + xc0)) * ND + d];
      float v11 = ft[((size_t)(yc1 * Wf + xc1)) * ND + d];
      float w00 = (vx0 && vy0) ? wx0 * wy0 : 0.f;
      float w10 = (vx1 && vy0) ? wx1 * wy0 : 0.f;
      float w01 = (vx0 && vy1) ? wx0 * wy1 : 0.f;
      float w11 = (vx1 && vy1) ? wx1 * wy1 : 0.f;
      float s = v00 * w00 + v10 * w10 + v01 * w01 + v11 * w11;
      acc = fmaf(a, s, acc);
    }
  }
  agg[(size_t)bq * 256 + d] = acc;
}

// ---------------- output projection: out = agg @ W_out + b_out ------------
// block = 128 threads, QBLK=16 queries; slot=(t&63) -> 4 cols, qg=(t>>6) -> 8 q
__global__ __launch_bounds__(128) void out_k(
    const float* __restrict__ agg, const float* __restrict__ W_out,
    const float* __restrict__ b_out, float* __restrict__ out) {
  int q0 = blockIdx.x * QBLK;
  __shared__ float as_[QBLK][ND];
  int t = threadIdx.x;
  {
    const float4* src = (const float4*)(agg + (size_t)q0 * ND);
    float4* dst = (float4*)&as_[0][0];
#pragma unroll
    for (int i = 0; i < 8; ++i) dst[t + 128 * i] = src[t + 128 * i];
  }
  __syncthreads();
  int slot = t & 63, qg = t >> 6;
  int j0 = slot << 2;
  float4 bb = *(const float4*)(b_out + j0);
  float4 acc[8];
#pragma unroll
  for (int qq = 0; qq < 8; ++qq) acc[qq] = bb;
  const float* abase = &as_[qg * 8][0];
#pragma unroll 4
  for (int k = 0; k < ND; ++k) {
    float4 w = *(const float4*)(W_out + (size_t)k * 256 + j0);
#pragma unroll
    for (int qq = 0; qq < 8; ++qq) {
      float ak = abase[qq * ND + k];
      acc[qq].x = fmaf(ak, w.x, acc[qq].x);
      acc[qq].y = fmaf(ak, w.y, acc[qq].y);
      acc[qq].z = fmaf(ak, w.z, acc[qq].z);
      acc[qq].w = fmaf(ak, w.w, acc[qq].w);
    }
  }
#pragma unroll
  for (int qq = 0; qq < 8; ++qq) {
    *(float4*)(out + (size_t)(q0 + qg * 8 + qq) * 256 + j0) = acc[qq];
  }
}

extern "C" void kernel_launch(void* const* d_in, const int* in_sizes, int n_in,
                              void* d_out, int out_size, void* d_ws,
                              size_t ws_size, hipStream_t stream) {
  const float* query  = (const float*)d_in[0];
  const float* feat0  = (const float*)d_in[1];
  const float* feat1  = (const float*)d_in[2];
  const float* feat2  = (const float*)d_in[3];
  const float* feat3  = (const float*)d_in[4];
  const float* refp   = (const float*)d_in[5];
  const float* W_off  = (const float*)d_in[6];
  const float* b_off  = (const float*)d_in[7];
  const float* W_attn = (const float*)d_in[8];
  const float* b_attn = (const float*)d_in[9];
  const float* W_out  = (const float*)d_in[10];
  const float* b_out  = (const float*)d_in[11];

  float* out = (float*)d_out;                      // (B, Q, D)
  float* attn_out = out + (size_t)NB * NQ * ND;    // (B, Q, H, L, P)

  float* ws  = (float*)d_ws;
  float* fT0 = ws;                                     // 4*16384*256
  float* fT1 = fT0 + (size_t)NB * 16384 * ND;          // 4*4096*256
  float* fT2 = fT1 + (size_t)NB * 4096 * ND;           // 4*1024*256
  float* fT3 = fT2 + (size_t)NB * 1024 * ND;           // 4*256*256
  float* pos = fT3 + (size_t)NB * 256 * ND;            // 4*8192*256
  float* agg = pos + (size_t)NB * NQ * ND;             // 4*8192*256

  transpose_k<<<dim3(512, 8, NB), 256, 0, stream>>>(feat0, fT0, 16384);
  transpose_k<<<dim3(128, 8, NB), 256, 0, stream>>>(feat1, fT1, 4096);
  transpose_k<<<dim3(32, 8, NB), 256, 0, stream>>>(feat2, fT2, 1024);
  transpose_k<<<dim3(8, 8, NB), 256, 0, stream>>>(feat3, fT3, 256);

  proj_k<<<dim3(NB * NQ / QBLK), 192, 0, stream>>>(query, refp, W_off, b_off,
                                                   W_attn, b_attn, pos,
                                                   attn_out);
  sample_k<<<dim3(NB * NQ), 256, 0, stream>>>(fT0, fT1, fT2, fT3, pos,
                                              attn_out, agg);
  out_k<<<dim3(NB * NQ / QBLK), 128, 0, stream>>>(agg, W_out, b_out, out);
}

// Round 5
// 466.982 us; speedup vs baseline: 1.0670x; 1.0670x over previous
//
#include <hip/hip_runtime.h>
#include <cstdint>
#include <cstddef>

#define NB 4
#define NQ 8192
#define ND 256
#define NH 8
#define NL 4
#define NP 4
#define QBLK 16
// HD = 32

// ---------------- transpose (B, D, HW) -> (B, HW, D) ----------------
__global__ __launch_bounds__(256) void transpose_k(
    const float* __restrict__ in, float* __restrict__ out, int HW) {
  __shared__ float tile[32][33];
  int yx0 = blockIdx.x << 5;
  int d0  = blockIdx.y << 5;
  int b   = blockIdx.z;
  const float* inb = in + (size_t)b * ND * HW;
  float* outb = out + (size_t)b * HW * ND;
  int col = threadIdx.x & 31;
  int row = threadIdx.x >> 5;  // 0..7
#pragma unroll
  for (int r = 0; r < 4; ++r) {
    int d = row + (r << 3);
    tile[d][col] = inb[(size_t)(d0 + d) * HW + (yx0 + col)];
  }
  __syncthreads();
#pragma unroll
  for (int r = 0; r < 4; ++r) {
    int y = row + (r << 3);
    outb[(size_t)(yx0 + y) * ND + (d0 + col)] = tile[col][y];
  }
}

// ---------------- proj: offsets(tanh)+ref -> pos, logits -> softmax attn ----
__global__ __launch_bounds__(192) void proj_k(
    const float* __restrict__ query, const float* __restrict__ refp,
    const float* __restrict__ W_off, const float* __restrict__ b_off,
    const float* __restrict__ W_attn, const float* __restrict__ b_attn,
    float* __restrict__ pos, float* __restrict__ attn_out) {
  int q0 = blockIdx.x * QBLK;
  __shared__ float qs[QBLK][ND];
  __shared__ float lg[QBLK][128];
  int t = threadIdx.x;
  {
    const float4* qsrc = (const float4*)(query + (size_t)q0 * ND);
    float4* qdst = (float4*)&qs[0][0];
#pragma unroll
    for (int i = 0; i < 6; ++i) {
      int idx = t + 192 * i;
      if (idx < QBLK * ND / 4) qdst[idx] = qsrc[idx];
    }
  }
  __syncthreads();
  if (t < 128) {
    int slot = t & 63, qg = t >> 6;
    int j0 = slot << 2;
    float4 bb = *(const float4*)(b_off + j0);
    float4 acc[8];
#pragma unroll
    for (int qq = 0; qq < 8; ++qq) acc[qq] = bb;
    const float* qbase = &qs[qg * 8][0];
#pragma unroll 4
    for (int k = 0; k < ND; ++k) {
      float4 w = *(const float4*)(W_off + (size_t)k * 256 + j0);
#pragma unroll
      for (int qq = 0; qq < 8; ++qq) {
        float qk = qbase[qq * ND + k];
        acc[qq].x = fmaf(qk, w.x, acc[qq].x);
        acc[qq].y = fmaf(qk, w.y, acc[qq].y);
        acc[qq].z = fmaf(qk, w.z, acc[qq].z);
        acc[qq].w = fmaf(qk, w.w, acc[qq].w);
      }
    }
#pragma unroll
    for (int qq = 0; qq < 8; ++qq) {
      int bq = q0 + qg * 8 + qq;
      float rx = refp[bq * 2 + 0] * 2.f - 1.f;
      float ry = refp[bq * 2 + 1] * 2.f - 1.f;
      float4 r;
      r.x = rx + tanhf(acc[qq].x);
      r.y = ry + tanhf(acc[qq].y);
      r.z = rx + tanhf(acc[qq].z);
      r.w = ry + tanhf(acc[qq].w);
      *(float4*)(pos + (size_t)bq * 256 + j0) = r;
    }
  } else {
    int u = t - 128;
    int slot = u & 31, qg = u >> 5;
    int j0 = slot << 2;
    float4 bb = *(const float4*)(b_attn + j0);
    float4 acc[8];
#pragma unroll
    for (int qq = 0; qq < 8; ++qq) acc[qq] = bb;
    const float* qbase = &qs[qg * 8][0];
#pragma unroll 4
    for (int k = 0; k < ND; ++k) {
      float4 w = *(const float4*)(W_attn + (size_t)k * 128 + j0);
#pragma unroll
      for (int qq = 0; qq < 8; ++qq) {
        float qk = qbase[qq * ND + k];
        acc[qq].x = fmaf(qk, w.x, acc[qq].x);
        acc[qq].y = fmaf(qk, w.y, acc[qq].y);
        acc[qq].z = fmaf(qk, w.z, acc[qq].z);
        acc[qq].w = fmaf(qk, w.w, acc[qq].w);
      }
    }
#pragma unroll
    for (int qq = 0; qq < 8; ++qq) {
      int qi = qg * 8 + qq;
      lg[qi][j0 + 0] = acc[qq].x;
      lg[qi][j0 + 1] = acc[qq].y;
      lg[qi][j0 + 2] = acc[qq].z;
      lg[qi][j0 + 3] = acc[qq].w;
    }
  }
  __syncthreads();
  if (t < 128) {
    int qi = t >> 3;
    int h = t & 7;
    float* l = &lg[qi][h * 16];
    float m = -1e30f;
#pragma unroll
    for (int i = 0; i < 16; ++i) m = fmaxf(m, l[i]);
    float e[16], s = 0.f;
#pragma unroll
    for (int i = 0; i < 16; ++i) { e[i] = __expf(l[i] - m); s += e[i]; }
    float inv = 1.f / s;
#pragma unroll
    for (int i = 0; i < 16; ++i) l[i] = e[i] * inv;
  }
  __syncthreads();
  {
    const float4* src = (const float4*)&lg[0][0];
    float4* dst = (float4*)(attn_out + (size_t)q0 * 128);
#pragma unroll
    for (int i = 0; i < 3; ++i) {
      int idx = t + 192 * i;
      if (idx < QBLK * 128 / 4) dst[idx] = src[idx];
    }
  }
}

// ---------------- sampling v2: 4 queries/block, LDS sample table ----------
// Phase 1: 512 (sample,corner-set) records -> LDS (premultiplied weights,
//          absolute element offsets into the unified transposed-feature ws).
// Phase 2: thread = (query-wave, head, channel-quad), float4 gathers.
#define HPAD 136  // 16 samples * 8 dwords + 8 pad (2-way-max LDS conflicts)
__global__ __launch_bounds__(256) void sample_k(
    const float* __restrict__ feat_ws, const float* __restrict__ pos,
    const float* __restrict__ attnw, float* __restrict__ agg) {
  __shared__ int tbl[4 * NH * HPAD];
  int bid = blockIdx.x;
  int wk = ((bid & 7) << 10) | (bid >> 3);  // XCD swizzle: grid 8192 = 8*1024
  int q0 = wk << 2;                          // 4 queries per block
  int b = wk >> 11;                          // batch (8192 q / batch)
  int t = threadIdx.x;

  // level bases (element offsets into unified feature workspace), incl. batch
  const int FT1 = NB * 16384 * ND;
  const int FT2 = FT1 + NB * 4096 * ND;
  const int FT3 = FT2 + NB * 1024 * ND;
  int lb[4] = {b * 16384 * ND, FT1 + b * 4096 * ND, FT2 + b * 1024 * ND,
               FT3 + b * 256 * ND};

#pragma unroll
  for (int j = t; j < 512; j += 256) {
    int qi = j >> 7, i = j & 127;  // i = h*16 + l*4 + p
    int bq = q0 + qi;
    float gx = pos[(size_t)bq * 256 + 2 * i];
    float gy = pos[(size_t)bq * 256 + 2 * i + 1];
    float a = attnw[(size_t)bq * 128 + i];
    int l = (i >> 2) & 3;
    int Wf = 128 >> l;
    float wf1 = (float)(Wf - 1);
    float x = (gx + 1.f) * 0.5f * wf1;
    float y = (gy + 1.f) * 0.5f * wf1;
    float x0f = floorf(x), y0f = floorf(y);
    float wx1 = x - x0f, wx0 = 1.f - wx1;
    float wy1 = y - y0f, wy0 = 1.f - wy1;
    int x0 = (int)x0f, y0 = (int)y0f;
    int x1 = x0 + 1, y1 = y0 + 1;
    bool vx0 = (x0 >= 0) && (x0 < Wf);
    bool vx1 = (x1 >= 0) && (x1 < Wf);
    bool vy0 = (y0 >= 0) && (y0 < Wf);
    bool vy1 = (y1 >= 0) && (y1 < Wf);
    int xc0 = min(max(x0, 0), Wf - 1), xc1 = min(max(x1, 0), Wf - 1);
    int yc0 = min(max(y0, 0), Wf - 1), yc1 = min(max(y1, 0), Wf - 1);
    int base = lb[l];
    int o00 = base + (yc0 * Wf + xc0) * ND;
    int o10 = base + (yc0 * Wf + xc1) * ND;
    int o01 = base + (yc1 * Wf + xc0) * ND;
    int o11 = base + (yc1 * Wf + xc1) * ND;
    float w00 = (vx0 && vy0) ? a * wx0 * wy0 : 0.f;
    float w10 = (vx1 && vy0) ? a * wx1 * wy0 : 0.f;
    float w01 = (vx0 && vy1) ? a * wx0 * wy1 : 0.f;
    float w11 = (vx1 && vy1) ? a * wx1 * wy1 : 0.f;
    int h = i >> 4, s = i & 15;
    int* rec = &tbl[(qi * NH + h) * HPAD + s * 8];
    rec[0] = o00; rec[1] = __float_as_int(w00);
    rec[2] = o10; rec[3] = __float_as_int(w10);
    rec[4] = o01; rec[5] = __float_as_int(w01);
    rec[6] = o11; rec[7] = __float_as_int(w11);
  }
  __syncthreads();

  int lane = t & 63, qi = t >> 6;
  int h = lane >> 3, cq = lane & 7;
  int bq = q0 + qi;
  int choff = (h << 5) + (cq << 2);
  const int* rec = &tbl[(qi * NH + h) * HPAD];
  float4 acc = {0.f, 0.f, 0.f, 0.f};
#pragma unroll 4
  for (int s = 0; s < 16; ++s) {
#pragma unroll
    for (int c = 0; c < 4; ++c) {
      int off = rec[s * 8 + c * 2];
      float w = __int_as_float(rec[s * 8 + c * 2 + 1]);
      float4 v = *(const float4*)(feat_ws + off + choff);
      acc.x = fmaf(w, v.x, acc.x);
      acc.y = fmaf(w, v.y, acc.y);
      acc.z = fmaf(w, v.z, acc.z);
      acc.w = fmaf(w, v.w, acc.w);
    }
  }
  *(float4*)(agg + (size_t)bq * 256 + choff) = acc;
}

// ---------------- output projection: out = agg @ W_out + b_out ------------
__global__ __launch_bounds__(128) void out_k(
    const float* __restrict__ agg, const float* __restrict__ W_out,
    const float* __restrict__ b_out, float* __restrict__ out) {
  int q0 = blockIdx.x * QBLK;
  __shared__ float as_[QBLK][ND];
  int t = threadIdx.x;
  {
    const float4* src = (const float4*)(agg + (size_t)q0 * ND);
    float4* dst = (float4*)&as_[0][0];
#pragma unroll
    for (int i = 0; i < 8; ++i) dst[t + 128 * i] = src[t + 128 * i];
  }
  __syncthreads();
  int slot = t & 63, qg = t >> 6;
  int j0 = slot << 2;
  float4 bb = *(const float4*)(b_out + j0);
  float4 acc[8];
#pragma unroll
  for (int qq = 0; qq < 8; ++qq) acc[qq] = bb;
  const float* abase = &as_[qg * 8][0];
#pragma unroll 4
  for (int k = 0; k < ND; ++k) {
    float4 w = *(const float4*)(W_out + (size_t)k * 256 + j0);
#pragma unroll
    for (int qq = 0; qq < 8; ++qq) {
      float ak = abase[qq * ND + k];
      acc[qq].x = fmaf(ak, w.x, acc[qq].x);
      acc[qq].y = fmaf(ak, w.y, acc[qq].y);
      acc[qq].z = fmaf(ak, w.z, acc[qq].z);
      acc[qq].w = fmaf(ak, w.w, acc[qq].w);
    }
  }
#pragma unroll
  for (int qq = 0; qq < 8; ++qq) {
    *(float4*)(out + (size_t)(q0 + qg * 8 + qq) * 256 + j0) = acc[qq];
  }
}

extern "C" void kernel_launch(void* const* d_in, const int* in_sizes, int n_in,
                              void* d_out, int out_size, void* d_ws,
                              size_t ws_size, hipStream_t stream) {
  const float* query  = (const float*)d_in[0];
  const float* feat0  = (const float*)d_in[1];
  const float* feat1  = (const float*)d_in[2];
  const float* feat2  = (const float*)d_in[3];
  const float* feat3  = (const float*)d_in[4];
  const float* refp   = (const float*)d_in[5];
  const float* W_off  = (const float*)d_in[6];
  const float* b_off  = (const float*)d_in[7];
  const float* W_attn = (const float*)d_in[8];
  const float* b_attn = (const float*)d_in[9];
  const float* W_out  = (const float*)d_in[10];
  const float* b_out  = (const float*)d_in[11];

  float* out = (float*)d_out;                      // (B, Q, D)
  float* attn_out = out + (size_t)NB * NQ * ND;    // (B, Q, H, L, P)

  float* ws  = (float*)d_ws;
  float* fT0 = ws;                                     // unified feature ws
  float* fT1 = fT0 + (size_t)NB * 16384 * ND;
  float* fT2 = fT1 + (size_t)NB * 4096 * ND;
  float* fT3 = fT2 + (size_t)NB * 1024 * ND;
  float* pos = fT3 + (size_t)NB * 256 * ND;            // 4*8192*256
  float* agg = pos + (size_t)NB * NQ * ND;             // 4*8192*256

  transpose_k<<<dim3(512, 8, NB), 256, 0, stream>>>(feat0, fT0, 16384);
  transpose_k<<<dim3(128, 8, NB), 256, 0, stream>>>(feat1, fT1, 4096);
  transpose_k<<<dim3(32, 8, NB), 256, 0, stream>>>(feat2, fT2, 1024);
  transpose_k<<<dim3(8, 8, NB), 256, 0, stream>>>(feat3, fT3, 256);

  proj_k<<<dim3(NB * NQ / QBLK), 192, 0, stream>>>(query, refp, W_off, b_off,
                                                   W_attn, b_attn, pos,
                                                   attn_out);
  sample_k<<<dim3(NB * NQ / 4), 256, 0, stream>>>(fT0, pos, attn_out, agg);
  out_k<<<dim3(NB * NQ / QBLK), 128, 0, stream>>>(agg, W_out, b_out, out);
}